// Round 1
// baseline (2363.275 us; speedup 1.0000x reference)
//
#include <hip/hip_runtime.h>
#include <hip/hip_bf16.h>

#define NODES 4097
#define TT 4096
#define CIN 64
#define HID 128
#define BATCH 64
#define EPS 1e-5f

// ---------------- transpose feats (B,C,N) -> fT (B,N,C) ----------------
__global__ __launch_bounds__(256) void k_transpose(const float* __restrict__ in,
                                                   float* __restrict__ out) {
    __shared__ float tile[32][33];
    int b = blockIdx.z;
    int n0 = blockIdx.x * 32;
    int c0 = blockIdx.y * 32;
    int tx = threadIdx.x, ty = threadIdx.y;  // (32,8)
    for (int i = 0; i < 32; i += 8) {
        int n = n0 + tx, c = c0 + ty + i;
        float v = 0.f;
        if (n < NODES) v = in[((size_t)b * CIN + c) * NODES + n];
        tile[ty + i][tx] = v;
    }
    __syncthreads();
    for (int i = 0; i < 32; i += 8) {
        int n = n0 + ty + i, c = c0 + tx;
        if (n < NODES) out[((size_t)b * NODES + n) * CIN + c] = tile[tx][ty + i];
    }
}

// ---------------- W (O,C,3) -> Wt (3*C, O), kc = k*C + c ----------------
__global__ void k_wtrans(const float* __restrict__ W, float* __restrict__ Wt, int C) {
    int id = blockIdx.x * 256 + threadIdx.x;
    int total = 3 * C * HID;
    if (id >= total) return;
    int o = id % HID;
    int kc = id / HID;
    int k = kc / C, c = kc % C;
    Wt[kc * HID + o] = W[(o * C + c) * 3 + k];
}

// ---------------- gather-conv ----------------
// block: 256 threads, handles (b = blockIdx.y, t in [t0, t0+32))
// thread register tile: 4 o x 4 t
template <int C, bool NORM>
__global__ __launch_bounds__(256) void k_conv(
    const float* __restrict__ xT,             // layer1 input (B,N,C) fp32
    const __hip_bfloat16* __restrict__ xTb,   // layer2 input (B,N,C) bf16 raw
    const int* __restrict__ children,
    const float* __restrict__ Wt,             // (3C, HID)
    const float* __restrict__ bias,           // (HID)
    const float* __restrict__ ms,             // per-b mean, inv(std+eps) (layer2)
    __hip_bfloat16* __restrict__ y,           // out (B,N,HID) raw (node0 = 0)
    float* __restrict__ sums) {               // [B][2] sum, sumsq accumulators
    const int b = blockIdx.y;
    const int t0 = blockIdx.x * 32;
    const int tid = threadIdx.x;

    __shared__ float g[3 * C * 33];  // rows kc = k*C+c, width 32 (+1 pad)

    float mean = 0.f, scale = 1.f;
    if (NORM) { mean = ms[b * 2]; scale = ms[b * 2 + 1]; }

    // ---- stage 96 gathered columns (t,k), each C floats, into LDS ----
    const int cpc = 256 / C;  // columns staged per iteration
    const int c = tid % C;
    const int col0 = tid / C;
    const long cbase = (long)b * (3 * TT) + (long)t0 * 3;
    for (int col = col0; col < 96; col += cpc) {
        int j = children[cbase + col];  // col = t*3 + k
        float v;
        if (!NORM) {
            v = xT[((size_t)b * NODES + j) * C + c];
        } else {
            v = __bfloat162float(xTb[((size_t)b * NODES + j) * C + c]);
            v = (v - mean) * scale;
            v = v > 0.f ? v : 0.f;
        }
        int t = col / 3, k = col % 3;
        g[(k * C + c) * 33 + t] = v;
    }
    __syncthreads();

    // ---- compute 4o x 4t per thread ----
    const int o4 = (tid & 31) * 4;
    const int t4 = (tid >> 5) * 4;
    float acc[4][4] = {};
#pragma unroll 4
    for (int kc = 0; kc < 3 * C; ++kc) {
        const float4 w = *reinterpret_cast<const float4*>(Wt + kc * HID + o4);
        float g0 = g[kc * 33 + t4 + 0];
        float g1 = g[kc * 33 + t4 + 1];
        float g2 = g[kc * 33 + t4 + 2];
        float g3 = g[kc * 33 + t4 + 3];
        acc[0][0] += w.x * g0; acc[0][1] += w.x * g1; acc[0][2] += w.x * g2; acc[0][3] += w.x * g3;
        acc[1][0] += w.y * g0; acc[1][1] += w.y * g1; acc[1][2] += w.y * g2; acc[1][3] += w.y * g3;
        acc[2][0] += w.z * g0; acc[2][1] += w.z * g1; acc[2][2] += w.z * g2; acc[2][3] += w.z * g3;
        acc[3][0] += w.w * g0; acc[3][1] += w.w * g1; acc[3][2] += w.w * g2; acc[3][3] += w.w * g3;
    }

    // ---- epilogue: bias, store bf16 (node index shifted +1), stats ----
    float bsum = 0.f, bss = 0.f;
#pragma unroll
    for (int oi = 0; oi < 4; ++oi) {
        float bv = bias[o4 + oi];
#pragma unroll
        for (int ti = 0; ti < 4; ++ti) {
            float v = acc[oi][ti] + bv;
            bsum += v;
            bss += v * v;
            y[((size_t)b * NODES + (t0 + t4 + ti + 1)) * HID + o4 + oi] = __float2bfloat16(v);
        }
    }
    if (blockIdx.x == 0 && tid < HID)
        y[((size_t)b * NODES) * HID + tid] = __float2bfloat16(0.f);

    __syncthreads();  // g reads done; reuse as reduction scratch
    float* red = g;
    red[tid] = bsum;
    red[256 + tid] = bss;
    __syncthreads();
    for (int s = 128; s > 0; s >>= 1) {
        if (tid < s) { red[tid] += red[tid + s]; red[256 + tid] += red[256 + tid + s]; }
        __syncthreads();
    }
    if (tid == 0) {
        atomicAdd(&sums[b * 2], red[0]);
        atomicAdd(&sums[b * 2 + 1], red[256]);
    }
}

// ---------------- per-b stats: sum,sumsq -> mean, 1/(std+eps) ----------------
__global__ void k_stats(const float* __restrict__ sums, float* __restrict__ ms) {
    int b = threadIdx.x;  // 64
    const float M = (float)HID * (float)NODES;
    float S = sums[b * 2], SS = sums[b * 2 + 1];
    float mean = S / M;
    float var = (SS - S * S / M) / (M - 1.f);
    float sd = sqrtf(fmaxf(var, 0.f));
    ms[b * 2] = mean;
    ms[b * 2 + 1] = 1.f / (sd + EPS);
}

// ---------------- max-pool over nodes of relu(norm(y)) ----------------
__global__ __launch_bounds__(256) void k_pool(const __hip_bfloat16* __restrict__ y,
                                              const float* __restrict__ ms,
                                              float* __restrict__ combined, int enc_off) {
    int b = blockIdx.x;
    int o = threadIdx.x & (HID - 1);
    int half = threadIdx.x >> 7;
    float mx = -1e30f;
    for (int n = half; n < NODES; n += 2)
        mx = fmaxf(mx, __bfloat162float(y[((size_t)b * NODES + n) * HID + o]));
    __shared__ float red[256];
    red[threadIdx.x] = mx;
    __syncthreads();
    if (half == 0) {
        // (x-mean)*scale is monotone (scale>0): max then transform then relu
        float m = fmaxf(red[o], red[HID + o]);
        float v = (m - ms[b * 2]) * ms[b * 2 + 1];
        combined[b * 2 * HID + enc_off + o] = v > 0.f ? v : 0.f;
    }
}

// ---------------- final FC: mu / logvar ----------------
__global__ __launch_bounds__(128) void k_fc(const float* __restrict__ combined,
                                            const float* __restrict__ Wmu, const float* __restrict__ bmu,
                                            const float* __restrict__ Wlv, const float* __restrict__ blv,
                                            float* __restrict__ out) {
    int b = blockIdx.x;
    int tid = threadIdx.x;
    __shared__ float cb[256];
    cb[tid] = combined[b * 256 + tid];
    cb[tid + 128] = combined[b * 256 + tid + 128];
    __syncthreads();
    const float* W = (tid < 64) ? Wmu : Wlv;
    int l = tid & 63;
    float s = (tid < 64) ? bmu[l] : blv[l];
    for (int j = 0; j < 256; ++j) s += cb[j] * W[l * 256 + j];
    out[(tid < 64 ? 0 : BATCH * 64) + b * 64 + l] = s;
}

extern "C" void kernel_launch(void* const* d_in, const int* in_sizes, int n_in,
                              void* d_out, int out_size, void* d_ws, size_t ws_size,
                              hipStream_t stream) {
    const int* children = (const int*)d_in[2];
    const float* Wmu = (const float*)d_in[11];
    const float* bmu = (const float*)d_in[12];
    const float* Wlv = (const float*)d_in[13];
    const float* blv = (const float*)d_in[14];

    // ---- workspace layout (256B aligned) ----
    char* ws = (char*)d_ws;
    size_t off = 0;
    auto alloc = [&](size_t bytes) { void* p = ws + off; off += (bytes + 255) & ~(size_t)255; return p; };
    float* sums = (float*)alloc(2 * 2 * BATCH * 2 * sizeof(float));  // [enc][layer][b][2]
    float* msbuf = (float*)alloc(2 * 2 * BATCH * 2 * sizeof(float));
    float* combined = (float*)alloc((size_t)BATCH * 256 * sizeof(float));
    float* Wt1 = (float*)alloc((size_t)3 * CIN * HID * sizeof(float));
    float* Wt2 = (float*)alloc((size_t)3 * HID * HID * sizeof(float));
    float* fT = (float*)alloc((size_t)BATCH * NODES * CIN * sizeof(float));
    __hip_bfloat16* y1 = (__hip_bfloat16*)alloc((size_t)BATCH * NODES * HID * sizeof(__hip_bfloat16));
    __hip_bfloat16* y2 = (__hip_bfloat16*)alloc((size_t)BATCH * NODES * HID * sizeof(__hip_bfloat16));

    hipMemsetAsync(sums, 0, 2 * 2 * BATCH * 2 * sizeof(float), stream);

    for (int enc = 0; enc < 2; ++enc) {
        const float* feats = (const float*)d_in[enc];
        const float* W1 = (const float*)d_in[3 + enc * 4];
        const float* b1 = (const float*)d_in[4 + enc * 4];
        const float* W2 = (const float*)d_in[5 + enc * 4];
        const float* b2 = (const float*)d_in[6 + enc * 4];
        float* sums1 = sums + (enc * 2 + 0) * BATCH * 2;
        float* sums2 = sums + (enc * 2 + 1) * BATCH * 2;
        float* ms1 = msbuf + (enc * 2 + 0) * BATCH * 2;
        float* ms2 = msbuf + (enc * 2 + 1) * BATCH * 2;

        k_transpose<<<dim3((NODES + 31) / 32, CIN / 32, BATCH), dim3(32, 8), 0, stream>>>(feats, fT);
        k_wtrans<<<(3 * CIN * HID + 255) / 256, 256, 0, stream>>>(W1, Wt1, CIN);
        k_wtrans<<<(3 * HID * HID + 255) / 256, 256, 0, stream>>>(W2, Wt2, HID);

        k_conv<CIN, false><<<dim3(TT / 32, BATCH), 256, 0, stream>>>(
            fT, nullptr, children, Wt1, b1, nullptr, y1, sums1);
        k_stats<<<1, BATCH, 0, stream>>>(sums1, ms1);
        k_conv<HID, true><<<dim3(TT / 32, BATCH), 256, 0, stream>>>(
            nullptr, y1, children, Wt2, b2, ms1, y2, sums2);
        k_stats<<<1, BATCH, 0, stream>>>(sums2, ms2);
        k_pool<<<BATCH, 256, 0, stream>>>(y2, ms2, combined, enc * HID);
    }

    k_fc<<<BATCH, 128, 0, stream>>>(combined, Wmu, bmu, Wlv, blv, (float*)d_out);
}

// Round 2
// 1130.594 us; speedup vs baseline: 2.0903x; 2.0903x over previous
//
#include <hip/hip_runtime.h>
#include <hip/hip_bf16.h>

#define NODES 4097
#define TT 4096
#define CIN 64
#define HID 128
#define BATCH 64
#define EPS 1e-5f

typedef short bf16x8 __attribute__((ext_vector_type(8)));   // 8 bf16 = 4 VGPRs
typedef float f32x16 __attribute__((ext_vector_type(16)));  // 32x32 acc

// ---------------- transpose feats (B,C,N) fp32 -> fT (B,N,C) bf16 ----------------
__global__ __launch_bounds__(256) void k_transpose(const float* __restrict__ in,
                                                   __hip_bfloat16* __restrict__ out) {
    __shared__ float tile[32][33];
    int b = blockIdx.z;
    int n0 = blockIdx.x * 32;
    int c0 = blockIdx.y * 32;
    int tx = threadIdx.x, ty = threadIdx.y;  // (32,8)
    for (int i = 0; i < 32; i += 8) {
        int n = n0 + tx, c = c0 + ty + i;
        float v = 0.f;
        if (n < NODES) v = in[((size_t)b * CIN + c) * NODES + n];
        tile[ty + i][tx] = v;
    }
    __syncthreads();
    for (int i = 0; i < 32; i += 8) {
        int n = n0 + ty + i, c = c0 + tx;
        if (n < NODES) out[((size_t)b * NODES + n) * CIN + c] = __float2bfloat16(tile[tx][ty + i]);
    }
}

// ---------------- W (HID,C,3) fp32 -> frag-major bf16 B-operand layout ----------------
// Wp id = (ks*4 + ct)*64 + lane, each id holds 8 bf16: B[k=ks*16+(lane>>5)*8+j][n=ct*32+(lane&31)]
// with k = slot*C + c  (kc ordering), B[k][n] = W[(n*C + c)*3 + slot]
__global__ void k_wprep(const float* __restrict__ W, __hip_bfloat16* __restrict__ Wp, int C) {
    int id = blockIdx.x * 256 + threadIdx.x;
    int total = 3 * C * HID / 8;  // one id per 16B frag-chunk
    if (id >= total) return;
    int lane = id & 63;
    int ct = (id >> 6) & 3;
    int ks = id >> 8;
    int n = ct * 32 + (lane & 31);
    int kb = ks * 16 + (lane >> 5) * 8;
    union { int4 i; __hip_bfloat16 h[8]; } u;
#pragma unroll
    for (int j = 0; j < 8; ++j) {
        int k = kb + j;
        int slot = k / C, c = k % C;
        u.h[j] = __float2bfloat16(W[(n * C + c) * 3 + slot]);
    }
    ((int4*)Wp)[id] = u.i;
}

// ---------------- gather-conv via MFMA ----------------
// block = 256 thr (4 waves 2x2), tile = 128 nodes x 128 out-ch, K = 3*C
// wave tile 64x64 = 2x2 of 32x32x16 mfma; A staged per child-slot in frag-major LDS (65-pad)
template <int C, bool NORM>
__global__ __launch_bounds__(256) void k_conv_mfma(
    const __hip_bfloat16* __restrict__ xTb,   // (B,N,C) bf16 (raw for NORM)
    const int* __restrict__ children,
    const __hip_bfloat16* __restrict__ Wp,    // frag-major weights
    const float* __restrict__ bias,
    const float* __restrict__ ms,             // per-b mean, inv(std+eps)
    __hip_bfloat16* __restrict__ y,           // (B,N,HID) raw out
    float* __restrict__ sums) {
    constexpr int KSc = C / 16;   // ksteps per slot-chunk
    constexpr int CH8 = C / 8;    // 16B chunks per gathered column
    const int b = blockIdx.y;
    const int t0 = blockIdx.x * 128;
    const int tid = threadIdx.x;
    const int lane = tid & 63;
    const int w = tid >> 6;
    const int rg2 = w >> 1;   // wave row-half
    const int ct2 = w & 1;    // wave col-half

    __shared__ __align__(16) ushort A_lds[4 * KSc * 65 * 8];

    float mean = 0.f, scale = 1.f;
    if (NORM) { mean = ms[b * 2]; scale = ms[b * 2 + 1]; }

    f32x16 acc[2][2] = {};

    const long cbase = (long)b * (3 * TT) + (long)t0 * 3;
    const int4* WpB = (const int4*)Wp;

    for (int slot = 0; slot < 3; ++slot) {
        if (slot) __syncthreads();
        // ---- stage 128 gathered columns (child slot `slot`) into frag-major LDS ----
#pragma unroll
        for (int it = 0; it < (128 * CH8) / 256; ++it) {
            int idx = it * 256 + tid;
            int t = idx / CH8;        // consecutive lanes -> consecutive c8: coalesced
            int c8 = idx % CH8;
            int child = children[cbase + t * 3 + slot];
            union { int4 i; __hip_bfloat16 h[8]; } u;
            u.i = *(const int4*)(xTb + ((size_t)b * NODES + child) * C + c8 * 8);
            if (NORM) {
#pragma unroll
                for (int j = 0; j < 8; ++j) {
                    float f = __bfloat162float(u.h[j]);
                    f = (f - mean) * scale;
                    u.h[j] = __float2bfloat16(f > 0.f ? f : 0.f);
                }
            }
            int ks = c8 >> 1, half = c8 & 1;
            int idx16 = ((t >> 5) * KSc + ks) * 65 + (t & 31) + 32 * half;
            ((int4*)A_lds)[idx16] = u.i;
        }
        __syncthreads();

        // ---- MFMA over this slot's K range ----
#pragma unroll
        for (int ks = 0; ks < KSc; ++ks) {
            int ksg = slot * KSc + ks;
            bf16x8 a0 = *(const bf16x8*)&A_lds[(((2 * rg2 + 0) * KSc + ks) * 65 + lane) * 8];
            bf16x8 a1 = *(const bf16x8*)&A_lds[(((2 * rg2 + 1) * KSc + ks) * 65 + lane) * 8];
            union { int4 i; bf16x8 v; } b0, b1;
            b0.i = WpB[(ksg * 4 + 2 * ct2 + 0) * 64 + lane];
            b1.i = WpB[(ksg * 4 + 2 * ct2 + 1) * 64 + lane];
            acc[0][0] = __builtin_amdgcn_mfma_f32_32x32x16_bf16(a0, b0.v, acc[0][0], 0, 0, 0);
            acc[0][1] = __builtin_amdgcn_mfma_f32_32x32x16_bf16(a0, b1.v, acc[0][1], 0, 0, 0);
            acc[1][0] = __builtin_amdgcn_mfma_f32_32x32x16_bf16(a1, b0.v, acc[1][0], 0, 0, 0);
            acc[1][1] = __builtin_amdgcn_mfma_f32_32x32x16_bf16(a1, b1.v, acc[1][1], 0, 0, 0);
        }
    }

    // ---- epilogue: bias, store bf16 (node +1 shift), stats ----
    float bsum = 0.f, bss = 0.f;
#pragma unroll
    for (int rgi = 0; rgi < 2; ++rgi) {
#pragma unroll
        for (int cti = 0; cti < 2; ++cti) {
            int o = 64 * ct2 + 32 * cti + (lane & 31);
            float bv = bias[o];
            int rbase = t0 + 64 * rg2 + 32 * rgi + 4 * (lane >> 5) + 1;
            f32x16 a = acc[rgi][cti];
#pragma unroll
            for (int reg = 0; reg < 16; ++reg) {
                int row = rbase + (reg & 3) + 8 * (reg >> 2);
                float v = a[reg] + bv;
                bsum += v;
                bss += v * v;
                y[((size_t)b * NODES + row) * HID + o] = __float2bfloat16(v);
            }
        }
    }
    if (blockIdx.x == 0 && tid < HID)
        y[(size_t)b * NODES * HID + tid] = __float2bfloat16(0.f);

    __syncthreads();
    float* red = (float*)A_lds;
    red[tid] = bsum;
    red[256 + tid] = bss;
    __syncthreads();
    for (int s = 128; s > 0; s >>= 1) {
        if (tid < s) { red[tid] += red[tid + s]; red[256 + tid] += red[256 + tid + s]; }
        __syncthreads();
    }
    if (tid == 0) {
        atomicAdd(&sums[b * 2], red[0]);
        atomicAdd(&sums[b * 2 + 1], red[256]);
    }
}

// ---------------- per-b stats: sum,sumsq -> mean, 1/(std+eps) ----------------
__global__ void k_stats(const float* __restrict__ sums, float* __restrict__ ms) {
    int b = threadIdx.x;  // 64
    const float M = (float)HID * (float)NODES;
    float S = sums[b * 2], SS = sums[b * 2 + 1];
    float mean = S / M;
    float var = (SS - S * S / M) / (M - 1.f);
    float sd = sqrtf(fmaxf(var, 0.f));
    ms[b * 2] = mean;
    ms[b * 2 + 1] = 1.f / (sd + EPS);
}

// ---------------- max-pool over nodes of relu(norm(y)) ----------------
__global__ __launch_bounds__(256) void k_pool(const __hip_bfloat16* __restrict__ y,
                                              const float* __restrict__ ms,
                                              float* __restrict__ combined, int enc_off) {
    int b = blockIdx.x;
    int o = threadIdx.x & (HID - 1);
    int half = threadIdx.x >> 7;
    float mx = -1e30f;
    for (int n = half; n < NODES; n += 2)
        mx = fmaxf(mx, __bfloat162float(y[((size_t)b * NODES + n) * HID + o]));
    __shared__ float red[256];
    red[threadIdx.x] = mx;
    __syncthreads();
    if (half == 0) {
        // (x-mean)*scale monotone (scale>0): max, then transform, then relu
        float m = fmaxf(red[o], red[HID + o]);
        float v = (m - ms[b * 2]) * ms[b * 2 + 1];
        combined[b * 2 * HID + enc_off + o] = v > 0.f ? v : 0.f;
    }
}

// ---------------- final FC: mu / logvar ----------------
__global__ __launch_bounds__(128) void k_fc(const float* __restrict__ combined,
                                            const float* __restrict__ Wmu, const float* __restrict__ bmu,
                                            const float* __restrict__ Wlv, const float* __restrict__ blv,
                                            float* __restrict__ out) {
    int b = blockIdx.x;
    int tid = threadIdx.x;
    __shared__ float cb[256];
    cb[tid] = combined[b * 256 + tid];
    cb[tid + 128] = combined[b * 256 + tid + 128];
    __syncthreads();
    const float* W = (tid < 64) ? Wmu : Wlv;
    int l = tid & 63;
    float s = (tid < 64) ? bmu[l] : blv[l];
    for (int j = 0; j < 256; ++j) s += cb[j] * W[l * 256 + j];
    out[(tid < 64 ? 0 : BATCH * 64) + b * 64 + l] = s;
}

extern "C" void kernel_launch(void* const* d_in, const int* in_sizes, int n_in,
                              void* d_out, int out_size, void* d_ws, size_t ws_size,
                              hipStream_t stream) {
    const int* children = (const int*)d_in[2];
    const float* Wmu = (const float*)d_in[11];
    const float* bmu = (const float*)d_in[12];
    const float* Wlv = (const float*)d_in[13];
    const float* blv = (const float*)d_in[14];

    // ---- workspace layout (256B aligned) ----
    char* ws = (char*)d_ws;
    size_t off = 0;
    auto alloc = [&](size_t bytes) { void* p = ws + off; off += (bytes + 255) & ~(size_t)255; return p; };
    float* sums = (float*)alloc(2 * 2 * BATCH * 2 * sizeof(float));  // [enc][layer][b][2]
    float* msbuf = (float*)alloc(2 * 2 * BATCH * 2 * sizeof(float));
    float* combined = (float*)alloc((size_t)BATCH * 256 * sizeof(float));
    __hip_bfloat16* Wp1 = (__hip_bfloat16*)alloc((size_t)3 * CIN * HID * sizeof(__hip_bfloat16));
    __hip_bfloat16* Wp2 = (__hip_bfloat16*)alloc((size_t)3 * HID * HID * sizeof(__hip_bfloat16));
    __hip_bfloat16* fT = (__hip_bfloat16*)alloc((size_t)BATCH * NODES * CIN * sizeof(__hip_bfloat16));
    __hip_bfloat16* y1 = (__hip_bfloat16*)alloc((size_t)BATCH * NODES * HID * sizeof(__hip_bfloat16));
    __hip_bfloat16* y2 = (__hip_bfloat16*)alloc((size_t)BATCH * NODES * HID * sizeof(__hip_bfloat16));

    hipMemsetAsync(sums, 0, 2 * 2 * BATCH * 2 * sizeof(float), stream);

    for (int enc = 0; enc < 2; ++enc) {
        const float* feats = (const float*)d_in[enc];
        const float* W1 = (const float*)d_in[3 + enc * 4];
        const float* b1 = (const float*)d_in[4 + enc * 4];
        const float* W2 = (const float*)d_in[5 + enc * 4];
        const float* b2 = (const float*)d_in[6 + enc * 4];
        float* sums1 = sums + (enc * 2 + 0) * BATCH * 2;
        float* sums2 = sums + (enc * 2 + 1) * BATCH * 2;
        float* ms1 = msbuf + (enc * 2 + 0) * BATCH * 2;
        float* ms2 = msbuf + (enc * 2 + 1) * BATCH * 2;

        k_transpose<<<dim3((NODES + 31) / 32, CIN / 32, BATCH), dim3(32, 8), 0, stream>>>(feats, fT);
        k_wprep<<<(3 * CIN * HID / 8 + 255) / 256, 256, 0, stream>>>(W1, Wp1, CIN);
        k_wprep<<<(3 * HID * HID / 8 + 255) / 256, 256, 0, stream>>>(W2, Wp2, HID);

        k_conv_mfma<CIN, false><<<dim3(TT / 128, BATCH), 256, 0, stream>>>(
            fT, children, Wp1, b1, nullptr, y1, sums1);
        k_stats<<<1, BATCH, 0, stream>>>(sums1, ms1);
        k_conv_mfma<HID, true><<<dim3(TT / 128, BATCH), 256, 0, stream>>>(
            y1, children, Wp2, b2, ms1, y2, sums2);
        k_stats<<<1, BATCH, 0, stream>>>(sums2, ms2);
        k_pool<<<BATCH, 256, 0, stream>>>(y2, ms2, combined, enc * HID);
    }

    k_fc<<<BATCH, 128, 0, stream>>>(combined, Wmu, bmu, Wlv, blv, (float*)d_out);
}

// Round 3
// 448.970 us; speedup vs baseline: 5.2638x; 2.5182x over previous
//
#include <hip/hip_runtime.h>
#include <hip/hip_bf16.h>

#define NODES 4097
#define TT 4096
#define CIN 64
#define HID 128
#define BATCH 64
#define EPS 1e-5f

typedef short bf16x8 __attribute__((ext_vector_type(8)));   // 8 bf16 = 4 VGPRs
typedef float f32x16 __attribute__((ext_vector_type(16)));  // 32x32 acc

// ---------------- transpose feats (B,C,N) fp32 -> fT (B,N,C) bf16 ----------------
__global__ __launch_bounds__(256) void k_transpose(const float* __restrict__ in,
                                                   __hip_bfloat16* __restrict__ out) {
    __shared__ float tile[32][33];
    int b = blockIdx.z;
    int n0 = blockIdx.x * 32;
    int c0 = blockIdx.y * 32;
    int tx = threadIdx.x, ty = threadIdx.y;  // (32,8)
    for (int i = 0; i < 32; i += 8) {
        int n = n0 + tx, c = c0 + ty + i;
        float v = 0.f;
        if (n < NODES) v = in[((size_t)b * CIN + c) * NODES + n];
        tile[ty + i][tx] = v;
    }
    __syncthreads();
    for (int i = 0; i < 32; i += 8) {
        int n = n0 + ty + i, c = c0 + tx;
        if (n < NODES) out[((size_t)b * NODES + n) * CIN + c] = __float2bfloat16(tile[tx][ty + i]);
    }
}

// ---------------- W (HID,C,3) fp32 -> frag-major bf16 B-operand layout ----------------
// Wp id = (ks*4 + ct)*64 + lane, each id holds 8 bf16: B[k=ks*16+(lane>>5)*8+j][n=ct*32+(lane&31)]
// with k = slot*C + c  (kc ordering), B[k][n] = W[(n*C + c)*3 + slot]
__global__ void k_wprep(const float* __restrict__ W, __hip_bfloat16* __restrict__ Wp, int C) {
    int id = blockIdx.x * 256 + threadIdx.x;
    int total = 3 * C * HID / 8;  // one id per 16B frag-chunk
    if (id >= total) return;
    int lane = id & 63;
    int ct = (id >> 6) & 3;
    int ks = id >> 8;
    int n = ct * 32 + (lane & 31);
    int kb = ks * 16 + (lane >> 5) * 8;
    union { int4 i; __hip_bfloat16 h[8]; } u;
#pragma unroll
    for (int j = 0; j < 8; ++j) {
        int k = kb + j;
        int slot = k / C, c = k % C;
        u.h[j] = __float2bfloat16(W[(n * C + c) * 3 + slot]);
    }
    ((int4*)Wp)[id] = u.i;
}

// ---------------- gather-conv via MFMA ----------------
// block = 256 thr (4 waves 2x2), tile = 128 nodes x 128 out-ch, K = 3*C
// wave tile 64x64 = 2x2 of 32x32x16 mfma; A staged per child-slot in frag-major LDS (65-pad)
// POOL: skip y write, emit per-block per-o max partials instead (pool fused).
template <int C, bool NORM, bool POOL>
__global__ __launch_bounds__(256) void k_conv_mfma(
    const __hip_bfloat16* __restrict__ xTb,   // (B,N,C) bf16 (raw for NORM)
    const int* __restrict__ children,
    const __hip_bfloat16* __restrict__ Wp,    // frag-major weights
    const float* __restrict__ bias,
    const float* __restrict__ ms,             // per-b mean, inv(std+eps)
    __hip_bfloat16* __restrict__ y,           // (B,N,HID) raw out (unused if POOL)
    float* __restrict__ sums,                 // [B][2] sum, sumsq accumulators
    float* __restrict__ pool_part) {          // [B][32][HID] per-block max (if POOL)
    constexpr int KSc = C / 16;   // ksteps per slot-chunk
    constexpr int CH8 = C / 8;    // 16B chunks per gathered column
    const int b = blockIdx.y;
    const int t0 = blockIdx.x * 128;
    const int tid = threadIdx.x;
    const int lane = tid & 63;
    const int w = tid >> 6;
    const int rg2 = w >> 1;   // wave row-half
    const int ct2 = w & 1;    // wave col-half

    __shared__ __align__(16) ushort A_lds[4 * KSc * 65 * 8];

    float mean = 0.f, scale = 1.f;
    if (NORM) { mean = ms[b * 2]; scale = ms[b * 2 + 1]; }

    f32x16 acc[2][2] = {};

    const long cbase = (long)b * (3 * TT) + (long)t0 * 3;
    const int4* WpB = (const int4*)Wp;

    for (int slot = 0; slot < 3; ++slot) {
        if (slot) __syncthreads();
        // ---- stage 128 gathered columns (child slot `slot`) into frag-major LDS ----
#pragma unroll
        for (int it = 0; it < (128 * CH8) / 256; ++it) {
            int idx = it * 256 + tid;
            int t = idx / CH8;        // consecutive lanes -> consecutive c8: coalesced
            int c8 = idx % CH8;
            int child = children[cbase + t * 3 + slot];
            union { int4 i; __hip_bfloat16 h[8]; } u;
            u.i = *(const int4*)(xTb + ((size_t)b * NODES + child) * C + c8 * 8);
            if (NORM) {
#pragma unroll
                for (int j = 0; j < 8; ++j) {
                    float f = __bfloat162float(u.h[j]);
                    f = (f - mean) * scale;
                    u.h[j] = __float2bfloat16(f > 0.f ? f : 0.f);
                }
            }
            int ks = c8 >> 1, half = c8 & 1;
            int idx16 = ((t >> 5) * KSc + ks) * 65 + (t & 31) + 32 * half;
            ((int4*)A_lds)[idx16] = u.i;
        }
        __syncthreads();

        // ---- MFMA over this slot's K range ----
#pragma unroll
        for (int ks = 0; ks < KSc; ++ks) {
            int ksg = slot * KSc + ks;
            bf16x8 a0 = *(const bf16x8*)&A_lds[(((2 * rg2 + 0) * KSc + ks) * 65 + lane) * 8];
            bf16x8 a1 = *(const bf16x8*)&A_lds[(((2 * rg2 + 1) * KSc + ks) * 65 + lane) * 8];
            union { int4 i; bf16x8 v; } b0, b1;
            b0.i = WpB[(ksg * 4 + 2 * ct2 + 0) * 64 + lane];
            b1.i = WpB[(ksg * 4 + 2 * ct2 + 1) * 64 + lane];
            acc[0][0] = __builtin_amdgcn_mfma_f32_32x32x16_bf16(a0, b0.v, acc[0][0], 0, 0, 0);
            acc[0][1] = __builtin_amdgcn_mfma_f32_32x32x16_bf16(a0, b1.v, acc[0][1], 0, 0, 0);
            acc[1][0] = __builtin_amdgcn_mfma_f32_32x32x16_bf16(a1, b0.v, acc[1][0], 0, 0, 0);
            acc[1][1] = __builtin_amdgcn_mfma_f32_32x32x16_bf16(a1, b1.v, acc[1][1], 0, 0, 0);
        }
    }

    // ---- epilogue: bias, stats, and (POOL ? per-o max : bf16 store) ----
    float bsum = 0.f, bss = 0.f;
    float lmax[2] = {-3.4e38f, -3.4e38f};
#pragma unroll
    for (int rgi = 0; rgi < 2; ++rgi) {
#pragma unroll
        for (int cti = 0; cti < 2; ++cti) {
            int o = 64 * ct2 + 32 * cti + (lane & 31);
            float bv = bias[o];
            int rbase = t0 + 64 * rg2 + 32 * rgi + 4 * (lane >> 5) + 1;
            f32x16 a = acc[rgi][cti];
#pragma unroll
            for (int reg = 0; reg < 16; ++reg) {
                float v = a[reg] + bv;
                bsum += v;
                bss += v * v;
                if (POOL) {
                    lmax[cti] = fmaxf(lmax[cti], v);
                } else {
                    int row = rbase + (reg & 3) + 8 * (reg >> 2);
                    y[((size_t)b * NODES + row) * HID + o] = __float2bfloat16(v);
                }
            }
        }
    }
    if (!POOL && blockIdx.x == 0 && tid < HID)
        y[(size_t)b * NODES * HID + tid] = __float2bfloat16(0.f);

    __syncthreads();  // MFMA reads of A_lds done; reuse as reduction scratch
    float* red = (float*)A_lds;          // [0..511]   sum/sumsq reduction
    float* pm = red + 512;               // [512..1023] per-o max slices
    red[tid] = bsum;
    red[256 + tid] = bss;
    if (POOL) {
        int slice = 2 * rg2 + (lane >> 5);
        pm[(64 * ct2 + (lane & 31)) * 4 + slice] = lmax[0];
        pm[(64 * ct2 + 32 + (lane & 31)) * 4 + slice] = lmax[1];
    }
    __syncthreads();
    for (int s = 128; s > 0; s >>= 1) {
        if (tid < s) { red[tid] += red[tid + s]; red[256 + tid] += red[256 + tid + s]; }
        __syncthreads();
    }
    if (tid == 0) {
        atomicAdd(&sums[b * 2], red[0]);
        atomicAdd(&sums[b * 2 + 1], red[256]);
    }
    if (POOL && tid < HID) {
        float m = fmaxf(fmaxf(pm[tid * 4], pm[tid * 4 + 1]),
                        fmaxf(pm[tid * 4 + 2], pm[tid * 4 + 3]));
        pool_part[((size_t)b * 32 + blockIdx.x) * HID + tid] = m;
    }
}

// ---------------- per-b stats: sum,sumsq -> mean, 1/(std+eps) ----------------
__global__ void k_stats(const float* __restrict__ sums, float* __restrict__ ms) {
    int b = threadIdx.x;  // 64
    const float M = (float)HID * (float)NODES;
    float S = sums[b * 2], SS = sums[b * 2 + 1];
    float mean = S / M;
    float var = (SS - S * S / M) / (M - 1.f);
    float sd = sqrtf(fmaxf(var, 0.f));
    ms[b * 2] = mean;
    ms[b * 2 + 1] = 1.f / (sd + EPS);
}

// ---------------- finalize pool: reduce 32 partials, norm+relu ----------------
__global__ __launch_bounds__(128) void k_pool_fin(const float* __restrict__ part,
                                                  const float* __restrict__ ms,
                                                  float* __restrict__ combined, int enc_off) {
    int b = blockIdx.x;
    int o = threadIdx.x;  // 128
    float m = 0.f;  // node-0 raw value is 0; include it here
#pragma unroll 4
    for (int s = 0; s < 32; ++s)
        m = fmaxf(m, part[((size_t)b * 32 + s) * HID + o]);
    // (x-mean)*scale monotone (scale>0): max, then transform, then relu
    float v = (m - ms[b * 2]) * ms[b * 2 + 1];
    combined[b * 2 * HID + enc_off + o] = v > 0.f ? v : 0.f;
}

// ---------------- final FC: mu / logvar ----------------
__global__ __launch_bounds__(128) void k_fc(const float* __restrict__ combined,
                                            const float* __restrict__ Wmu, const float* __restrict__ bmu,
                                            const float* __restrict__ Wlv, const float* __restrict__ blv,
                                            float* __restrict__ out) {
    int b = blockIdx.x;
    int tid = threadIdx.x;
    __shared__ float cb[256];
    cb[tid] = combined[b * 256 + tid];
    cb[tid + 128] = combined[b * 256 + tid + 128];
    __syncthreads();
    const float* W = (tid < 64) ? Wmu : Wlv;
    int l = tid & 63;
    float s = (tid < 64) ? bmu[l] : blv[l];
    for (int j = 0; j < 256; ++j) s += cb[j] * W[l * 256 + j];
    out[(tid < 64 ? 0 : BATCH * 64) + b * 64 + l] = s;
}

extern "C" void kernel_launch(void* const* d_in, const int* in_sizes, int n_in,
                              void* d_out, int out_size, void* d_ws, size_t ws_size,
                              hipStream_t stream) {
    const int* children = (const int*)d_in[2];
    const float* Wmu = (const float*)d_in[11];
    const float* bmu = (const float*)d_in[12];
    const float* Wlv = (const float*)d_in[13];
    const float* blv = (const float*)d_in[14];

    // ---- workspace layout (256B aligned) ----
    char* ws = (char*)d_ws;
    size_t off = 0;
    auto alloc = [&](size_t bytes) { void* p = ws + off; off += (bytes + 255) & ~(size_t)255; return p; };
    float* sums = (float*)alloc(2 * 2 * BATCH * 2 * sizeof(float));  // [enc][layer][b][2]
    float* msbuf = (float*)alloc(2 * 2 * BATCH * 2 * sizeof(float));
    float* combined = (float*)alloc((size_t)BATCH * 256 * sizeof(float));
    float* pool_part = (float*)alloc((size_t)BATCH * 32 * HID * sizeof(float));
    __hip_bfloat16* Wp1 = (__hip_bfloat16*)alloc((size_t)3 * CIN * HID * sizeof(__hip_bfloat16));
    __hip_bfloat16* Wp2 = (__hip_bfloat16*)alloc((size_t)3 * HID * HID * sizeof(__hip_bfloat16));
    __hip_bfloat16* fT = (__hip_bfloat16*)alloc((size_t)BATCH * NODES * CIN * sizeof(__hip_bfloat16));
    __hip_bfloat16* y1 = (__hip_bfloat16*)alloc((size_t)BATCH * NODES * HID * sizeof(__hip_bfloat16));

    hipMemsetAsync(sums, 0, 2 * 2 * BATCH * 2 * sizeof(float), stream);

    for (int enc = 0; enc < 2; ++enc) {
        const float* feats = (const float*)d_in[enc];
        const float* W1 = (const float*)d_in[3 + enc * 4];
        const float* b1 = (const float*)d_in[4 + enc * 4];
        const float* W2 = (const float*)d_in[5 + enc * 4];
        const float* b2 = (const float*)d_in[6 + enc * 4];
        float* sums1 = sums + (enc * 2 + 0) * BATCH * 2;
        float* sums2 = sums + (enc * 2 + 1) * BATCH * 2;
        float* ms1 = msbuf + (enc * 2 + 0) * BATCH * 2;
        float* ms2 = msbuf + (enc * 2 + 1) * BATCH * 2;

        k_transpose<<<dim3((NODES + 31) / 32, CIN / 32, BATCH), dim3(32, 8), 0, stream>>>(feats, fT);
        k_wprep<<<(3 * CIN * HID / 8 + 255) / 256, 256, 0, stream>>>(W1, Wp1, CIN);
        k_wprep<<<(3 * HID * HID / 8 + 255) / 256, 256, 0, stream>>>(W2, Wp2, HID);

        k_conv_mfma<CIN, false, false><<<dim3(TT / 128, BATCH), 256, 0, stream>>>(
            fT, children, Wp1, b1, nullptr, y1, sums1, nullptr);
        k_stats<<<1, BATCH, 0, stream>>>(sums1, ms1);
        k_conv_mfma<HID, true, true><<<dim3(TT / 128, BATCH), 256, 0, stream>>>(
            y1, children, Wp2, b2, ms1, nullptr, sums2, pool_part);
        k_stats<<<1, BATCH, 0, stream>>>(sums2, ms2);
        k_pool_fin<<<BATCH, 128, 0, stream>>>(pool_part, ms2, combined, enc * HID);
    }

    k_fc<<<BATCH, 128, 0, stream>>>(combined, Wmu, bmu, Wlv, blv, (float*)d_out);
}

// Round 5
// 438.564 us; speedup vs baseline: 5.3887x; 1.0237x over previous
//
#include <hip/hip_runtime.h>
#include <hip/hip_bf16.h>

#define NODES 4097
#define TT 4096
#define CIN 64
#define HID 128
#define BATCH 64
#define EPS 1e-5f

typedef short bf16x8 __attribute__((ext_vector_type(8)));   // 8 bf16 = 4 VGPRs
typedef float f32x16 __attribute__((ext_vector_type(16)));  // 32x32 acc

// async global->LDS DMA, 16 B per lane; LDS dst = wave-uniform base + lane*16
__device__ __forceinline__ void load_lds16(const void* g, void* l) {
    __builtin_amdgcn_global_load_lds(
        (const __attribute__((address_space(1))) unsigned int*)(uintptr_t)g,
        (__attribute__((address_space(3))) unsigned int*)(uintptr_t)l,
        16, 0, 0);
}

// ---------------- transpose feats (B,C,N) fp32 -> fT (B,N,C) bf16, both encoders ----------------
__global__ __launch_bounds__(256) void k_transpose(const float* __restrict__ f0,
                                                   const float* __restrict__ f1,
                                                   __hip_bfloat16* __restrict__ out) {
    __shared__ float tile[32][33];
    int z = blockIdx.z;
    int enc = z >> 6, b = z & 63;
    const float* in = enc ? f1 : f0;
    __hip_bfloat16* o = out + (size_t)enc * BATCH * NODES * CIN;
    int n0 = blockIdx.x * 32;
    int c0 = blockIdx.y * 32;
    int tx = threadIdx.x, ty = threadIdx.y;  // (32,8)
    for (int i = 0; i < 32; i += 8) {
        int n = n0 + tx, c = c0 + ty + i;
        float v = 0.f;
        if (n < NODES) v = in[((size_t)b * CIN + c) * NODES + n];
        tile[ty + i][tx] = v;
    }
    __syncthreads();
    for (int i = 0; i < 32; i += 8) {
        int n = n0 + ty + i, c = c0 + tx;
        if (n < NODES) o[((size_t)b * NODES + n) * CIN + c] = __float2bfloat16(tile[tx][ty + i]);
    }
}

// ---------------- W (HID,C,3) fp32 -> frag-major bf16 B-operand layout, both encoders ----------------
// Wp id = (ks*4 + ct)*64 + lane holds 8 bf16: B[k=ks*16+(lane>>5)*8+j][n=ct*32+(lane&31)]
// k = slot*C + c; B[k][n] = W[(n*C + c)*3 + slot]
__global__ void k_wprep(const float* __restrict__ W0, const float* __restrict__ W1,
                        __hip_bfloat16* __restrict__ Wp, int C) {
    int enc = blockIdx.y;
    const float* W = enc ? W1 : W0;
    __hip_bfloat16* o = Wp + (size_t)enc * 3 * C * HID;
    int id = blockIdx.x * 256 + threadIdx.x;
    int total = 3 * C * HID / 8;
    if (id >= total) return;
    int lane = id & 63;
    int ct = (id >> 6) & 3;
    int ks = id >> 8;
    int n = ct * 32 + (lane & 31);
    int kb = ks * 16 + (lane >> 5) * 8;
    union { int4 i; __hip_bfloat16 h[8]; } u;
#pragma unroll
    for (int j = 0; j < 8; ++j) {
        int k = kb + j;
        int slot = k / C, c = k % C;
        u.h[j] = __float2bfloat16(W[(n * C + c) * 3 + slot]);
    }
    ((int4*)o)[id] = u.i;
}

// ---------------- gather-conv via MFMA + global_load_lds ----------------
// block = 256 thr (4 waves 2x2), tile = 128 nodes x 128 out-ch, K = 3*C
// A staged via DMA in lane-linear 1-KB chunks: chunk (tb,kk) = 32 nodes x 1 kstep,
// lane l -> (node tb*32+(l&31), k-octet l>>5); wave w stages node-block tb=w.
// MFMA A-frag read is then exactly lane-linear b128 (m=lane&31, octet=lane>>5).
template <int C, bool POOL>
__global__ __launch_bounds__(256) void k_conv_mfma(
    const __hip_bfloat16* __restrict__ xT,    // [2][B][N][C]
    const int* __restrict__ children,
    const __hip_bfloat16* __restrict__ Wp,    // [2][3C*HID] frag-major
    const float* __restrict__ bias0, const float* __restrict__ bias1,
    __hip_bfloat16* __restrict__ y,           // [2][B][N][HID] raw out (if !POOL)
    float* __restrict__ sums,                 // [2B][2]
    float* __restrict__ pool_part) {          // [2B][32][HID] (if POOL)
    constexpr int KSc = C / 16;             // ksteps per child-slot
    constexpr int TOTK = 3 * KSc;           // 12 or 24 ksteps
    constexpr int NPH = (C == 64) ? 1 : 3;  // staging phases
    constexpr int PK = TOTK / NPH;          // ksteps per phase
    const int b = blockIdx.y;
    const int enc = blockIdx.z;
    const int t0 = blockIdx.x * 128;
    const int tid = threadIdx.x;
    const int lane = tid & 63;
    const int w = tid >> 6;
    const int rg2 = w >> 1, ct2 = w & 1;

    __shared__ __align__(16) char A_lds[4 * PK * 1024];

    const __hip_bfloat16* x = xT + (size_t)enc * BATCH * NODES * C;
    const int4* WpB = (const int4*)(Wp + (size_t)enc * 3 * C * HID);
    const float* bias = enc ? bias1 : bias0;
    const int sb = enc * BATCH + b;

    f32x16 acc[2][2] = {};
    const size_t rowbase = (size_t)b * NODES;
    const long cb3 = (long)b * (3 * TT);
    const int tnode = t0 + w * 32 + (lane & 31);  // node this lane stages

    for (int ph = 0; ph < NPH; ++ph) {
        if (ph) __syncthreads();  // prior MFMA reads done before overwrite
#pragma unroll
        for (int kk = 0; kk < PK; ++kk) {
            int ksg = ph * PK + kk;
            int slot = ksg / KSc, ksl = ksg % KSc;
            int child = children[cb3 + (long)tnode * 3 + slot];
            const char* g = (const char*)(x + (rowbase + child) * C)
                          + ksl * 32 + (lane >> 5) * 16;
            load_lds16(g, A_lds + (w * PK + kk) * 1024);
        }
        __syncthreads();  // drains DMA (vmcnt) + barrier
#pragma unroll
        for (int kk = 0; kk < PK; ++kk) {
            int ksg = ph * PK + kk;
            bf16x8 a0 = *(const bf16x8*)(A_lds + ((2 * rg2 + 0) * PK + kk) * 1024 + lane * 16);
            bf16x8 a1 = *(const bf16x8*)(A_lds + ((2 * rg2 + 1) * PK + kk) * 1024 + lane * 16);
            union { int4 i; bf16x8 v; } b0, b1;
            b0.i = WpB[(ksg * 4 + 2 * ct2 + 0) * 64 + lane];
            b1.i = WpB[(ksg * 4 + 2 * ct2 + 1) * 64 + lane];
            acc[0][0] = __builtin_amdgcn_mfma_f32_32x32x16_bf16(a0, b0.v, acc[0][0], 0, 0, 0);
            acc[0][1] = __builtin_amdgcn_mfma_f32_32x32x16_bf16(a0, b1.v, acc[0][1], 0, 0, 0);
            acc[1][0] = __builtin_amdgcn_mfma_f32_32x32x16_bf16(a1, b0.v, acc[1][0], 0, 0, 0);
            acc[1][1] = __builtin_amdgcn_mfma_f32_32x32x16_bf16(a1, b1.v, acc[1][1], 0, 0, 0);
        }
    }

    // ---- epilogue: bias, stats, and (POOL ? per-o max : bf16 store) ----
    float bsum = 0.f, bss = 0.f;
    float lmax[2] = {-3.4e38f, -3.4e38f};
    __hip_bfloat16* yp = POOL ? nullptr : (y + (size_t)enc * BATCH * NODES * HID);
#pragma unroll
    for (int rgi = 0; rgi < 2; ++rgi) {
#pragma unroll
        for (int cti = 0; cti < 2; ++cti) {
            int o = 64 * ct2 + 32 * cti + (lane & 31);
            float bv = bias[o];
            int rbase = t0 + 64 * rg2 + 32 * rgi + 4 * (lane >> 5) + 1;
            f32x16 a = acc[rgi][cti];
#pragma unroll
            for (int reg = 0; reg < 16; ++reg) {
                float v = a[reg] + bv;
                bsum += v;
                bss += v * v;
                if (POOL) {
                    lmax[cti] = fmaxf(lmax[cti], v);
                } else {
                    int row = rbase + (reg & 3) + 8 * (reg >> 2);
                    yp[(rowbase + row) * HID + o] = __float2bfloat16(v);
                }
            }
        }
    }
    if (!POOL && blockIdx.x == 0 && tid < HID)
        yp[rowbase * HID + tid] = __float2bfloat16(0.f);

    __syncthreads();  // LDS reads done; reuse as reduction scratch
    float* red = (float*)A_lds;          // [0..511] sum/sumsq
    float* pm = red + 512;               // [512..1023] per-o max slices
    red[tid] = bsum;
    red[256 + tid] = bss;
    if (POOL) {
        int slice = 2 * rg2 + (lane >> 5);
        pm[(64 * ct2 + (lane & 31)) * 4 + slice] = lmax[0];
        pm[(64 * ct2 + 32 + (lane & 31)) * 4 + slice] = lmax[1];
    }
    __syncthreads();
    for (int s = 128; s > 0; s >>= 1) {
        if (tid < s) { red[tid] += red[tid + s]; red[256 + tid] += red[256 + tid + s]; }
        __syncthreads();
    }
    if (tid == 0) {
        atomicAdd(&sums[sb * 2], red[0]);
        atomicAdd(&sums[sb * 2 + 1], red[256]);
    }
    if (POOL && tid < HID) {
        float m = fmaxf(fmaxf(pm[tid * 4], pm[tid * 4 + 1]),
                        fmaxf(pm[tid * 4 + 2], pm[tid * 4 + 3]));
        pool_part[((size_t)sb * 32 + blockIdx.x) * HID + tid] = m;
    }
}

// ---------------- per-(enc,b) stats: sum,sumsq -> mean, 1/(std+eps) ----------------
__global__ void k_stats(const float* __restrict__ sums, float* __restrict__ ms) {
    int s = threadIdx.x;  // 128 = 2 enc x 64 b
    const float M = (float)HID * (float)NODES;
    float S = sums[s * 2], SS = sums[s * 2 + 1];
    float mean = S / M;
    float var = (SS - S * S / M) / (M - 1.f);
    float sd = sqrtf(fmaxf(var, 0.f));
    ms[s * 2] = mean;
    ms[s * 2 + 1] = 1.f / (sd + EPS);
}

// ---------------- in-place norm+relu of y1 (bf16 x8 vectorized) ----------------
__global__ __launch_bounds__(256) void k_norm(__hip_bfloat16* __restrict__ y,
                                              const float* __restrict__ ms) {
    constexpr int Q = NODES * HID / 8;  // 65552 int4s per (enc,b) slice
    int s = blockIdx.y;                 // enc*64 + b
    int q = blockIdx.x * 256 + threadIdx.x;
    if (q >= Q) return;
    float mean = ms[s * 2], scale = ms[s * 2 + 1];
    int4* p = (int4*)(y + (size_t)s * NODES * HID) + q;
    union { int4 i; __hip_bfloat16 h[8]; } u;
    u.i = *p;
#pragma unroll
    for (int j = 0; j < 8; ++j) {
        float f = (__bfloat162float(u.h[j]) - mean) * scale;
        u.h[j] = __float2bfloat16(f > 0.f ? f : 0.f);
    }
    *p = u.i;
}

// ---------------- finalize pool: reduce 32 partials, norm+relu ----------------
__global__ __launch_bounds__(128) void k_pool_fin(const float* __restrict__ part,
                                                  const float* __restrict__ ms1,
                                                  float* __restrict__ combined) {
    int b = blockIdx.x, enc = blockIdx.y, o = threadIdx.x;
    int sb = enc * BATCH + b;
    float m = 0.f;  // node-0 raw value is 0
#pragma unroll 4
    for (int s = 0; s < 32; ++s)
        m = fmaxf(m, part[((size_t)sb * 32 + s) * HID + o]);
    float v = (m - ms1[sb * 2]) * ms1[sb * 2 + 1];  // monotone: max then transform
    combined[b * 256 + enc * 128 + o] = v > 0.f ? v : 0.f;
}

// ---------------- final FC: mu / logvar ----------------
__global__ __launch_bounds__(128) void k_fc(const float* __restrict__ combined,
                                            const float* __restrict__ Wmu, const float* __restrict__ bmu,
                                            const float* __restrict__ Wlv, const float* __restrict__ blv,
                                            float* __restrict__ out) {
    int b = blockIdx.x;
    int tid = threadIdx.x;
    __shared__ float cb[256];
    cb[tid] = combined[b * 256 + tid];
    cb[tid + 128] = combined[b * 256 + tid + 128];
    __syncthreads();
    const float* W = (tid < 64) ? Wmu : Wlv;
    int l = tid & 63;
    float s = (tid < 64) ? bmu[l] : blv[l];
    for (int j = 0; j < 256; ++j) s += cb[j] * W[l * 256 + j];
    out[(tid < 64 ? 0 : BATCH * 64) + b * 64 + l] = s;
}

extern "C" void kernel_launch(void* const* d_in, const int* in_sizes, int n_in,
                              void* d_out, int out_size, void* d_ws, size_t ws_size,
                              hipStream_t stream) {
    const int* children = (const int*)d_in[2];
    const float* Wmu = (const float*)d_in[11];
    const float* bmu = (const float*)d_in[12];
    const float* Wlv = (const float*)d_in[13];
    const float* blv = (const float*)d_in[14];

    // ---- workspace layout (256B aligned) ----
    char* ws = (char*)d_ws;
    size_t off = 0;
    auto alloc = [&](size_t bytes) { void* p = ws + off; off += (bytes + 255) & ~(size_t)255; return p; };
    float* sums = (float*)alloc(2 * 2 * BATCH * 2 * sizeof(float));  // [layer][enc*B+b][2]
    float* msbuf = (float*)alloc(2 * 2 * BATCH * 2 * sizeof(float));
    float* combined = (float*)alloc((size_t)BATCH * 256 * sizeof(float));
    float* pool_part = (float*)alloc((size_t)2 * BATCH * 32 * HID * sizeof(float));
    __hip_bfloat16* Wp1 = (__hip_bfloat16*)alloc((size_t)2 * 3 * CIN * HID * sizeof(__hip_bfloat16));
    __hip_bfloat16* Wp2 = (__hip_bfloat16*)alloc((size_t)2 * 3 * HID * HID * sizeof(__hip_bfloat16));
    __hip_bfloat16* fT = (__hip_bfloat16*)alloc((size_t)2 * BATCH * NODES * CIN * sizeof(__hip_bfloat16));
    __hip_bfloat16* y1 = (__hip_bfloat16*)alloc((size_t)2 * BATCH * NODES * HID * sizeof(__hip_bfloat16));

    hipMemsetAsync(sums, 0, 2 * 2 * BATCH * 2 * sizeof(float), stream);

    k_wprep<<<dim3(3 * CIN * HID / 8 / 256, 2), 256, 0, stream>>>(
        (const float*)d_in[3], (const float*)d_in[7], Wp1, CIN);
    k_wprep<<<dim3(3 * HID * HID / 8 / 256, 2), 256, 0, stream>>>(
        (const float*)d_in[5], (const float*)d_in[9], Wp2, HID);
    k_transpose<<<dim3(129, 2, 2 * BATCH), dim3(32, 8), 0, stream>>>(
        (const float*)d_in[0], (const float*)d_in[1], fT);

    k_conv_mfma<CIN, false><<<dim3(TT / 128, BATCH, 2), 256, 0, stream>>>(
        fT, children, Wp1, (const float*)d_in[4], (const float*)d_in[8], y1, sums, nullptr);
    k_stats<<<1, 128, 0, stream>>>(sums, msbuf);
    k_norm<<<dim3((NODES * HID / 8 + 255) / 256, 2 * BATCH), 256, 0, stream>>>(y1, msbuf);
    k_conv_mfma<HID, true><<<dim3(TT / 128, BATCH, 2), 256, 0, stream>>>(
        y1, children, Wp2, (const float*)d_in[6], (const float*)d_in[10], nullptr,
        sums + 256, pool_part);
    k_stats<<<1, 128, 0, stream>>>(sums + 256, msbuf + 256);
    k_pool_fin<<<dim3(BATCH, 2), 128, 0, stream>>>(pool_part, msbuf + 256, combined);

    k_fc<<<BATCH, 128, 0, stream>>>(combined, Wmu, bmu, Wlv, blv, (float*)d_out);
}